// Round 7
// baseline (4403.147 us; speedup 1.0000x reference)
//
#include <hip/hip_runtime.h>
#include <cstdint>
#include <cstddef>

#define DD 768
#define SS 128
#define NNODE 12288            // 3*B*S
#define NBS 4096               // B*S
#define NBSD 3145728           // B*S*D (per-chunk elements)
#define TOTAL_ND 9437184ULL    // NNODE*DD == out_size (fp32 elements)

__device__ __forceinline__ float b2f(uint16_t u) {
    union { uint32_t i; float f; } x; x.i = ((uint32_t)u) << 16; return x.f;
}
__device__ __forceinline__ uint16_t f2b(float f) {
    uint32_t x = __float_as_uint(f);
    return (uint16_t)((x + 0x7FFFu + ((x >> 16) & 1u)) >> 16);
}
__device__ __forceinline__ float loadf(const void* p, size_t i, int isf32) {
    return isf32 ? ((const float*)p)[i] : b2f(((const uint16_t*)p)[i]);
}
// feats[n][d] = src_{d%3}[n*256 + d/3]
__device__ __forceinline__ float featAt(const void* hc, const void* hd, const void* hs,
                                        int n, int d, int isf) {
    int w = d % 3;
    size_t u = (size_t)n * 256 + (size_t)(d / 3);
    const void* p = (w == 0) ? hc : (w == 1) ? hd : hs;
    return loadf(p, u, isf);
}

// ---------- diag beacon (fp32 out now) ----------
__global__ void k_diag(float* out, float code) {
    if (threadIdx.x == 0 && blockIdx.x == 0) out[0] = code;
}

// ---------- dtype probe (fp32 vs bf16 input arrays) ----------
__global__ void k_probe(const void* hf, int* flag) {
    if (threadIdx.x == 0 && blockIdx.x == 0) {
        const uint32_t* w = (const uint32_t*)hf;
        int bad = 0;
        for (int k = 0; k < 64; k++) {
            uint16_t lo = (uint16_t)(w[k] & 0xFFFFu);
            int e = (lo >> 7) & 0xFF;
            if (e < 100 || e > 140) bad++;
        }
        flag[0] = (bad > 24) ? 1 : 0;
    }
}

// ---------- feats build (bf16 store; used as GEMM-A for xw) ----------
__global__ __launch_bounds__(256) void k_build_feats(
    const void* __restrict__ hc, const void* __restrict__ hd,
    const void* __restrict__ hs, uint16_t* __restrict__ feats,
    const int* __restrict__ flag) {
    int u = blockIdx.x * 256 + threadIdx.x;
    int isf = flag[0];
    if (u < NBSD) {
        feats[3 * (size_t)u + 0] = f2b(loadf(hc, u, isf));
        feats[3 * (size_t)u + 1] = f2b(loadf(hd, u, isf));
        feats[3 * (size_t)u + 2] = f2b(loadf(hs, u, isf));
    }
}

// ---------- exact fp32 node norms (first 128 nodes) ----------
__global__ void k_nrm2(const void* hc, const void* hd, const void* hs,
                       float* nrm, const int* flag) {
    int n = threadIdx.x;   // <<<1,128>>>
    int isf = flag[0];
    float s = 0.f;
    for (int d = 0; d < DD; d++) { float v = featAt(hc, hd, hs, n, d, isf); s += v * v; }
    nrm[n] = fmaxf(sqrtf(s), 1e-8f);
}

// ---------- exact fp32 cosine sims, one thread per edge ----------
__global__ __launch_bounds__(256) void k_sim2(const void* hc, const void* hd, const void* hs,
                                              const float* nrm, float* simb, const int* flag) {
    int e = blockIdx.x * 256 + threadIdx.x;   // <<<64,256>>>
    if (e >= SS * SS) return;
    int i = e >> 7, j = e & 127;
    int isf = flag[0];
    float s = 0.f;
    for (int d = 0; d < DD; d++)
        s += featAt(hc, hd, hs, i, d, isf) * featAt(hc, hd, hs, j, d, isf);
    simb[e] = s / (nrm[i] * nrm[j]);
}

// ---------- min/max over 16384 sims ----------
__global__ __launch_bounds__(256) void k_minmax(const float* __restrict__ simb,
                                                float* __restrict__ mnmx) {
    int tid = threadIdx.x;
    float mn = 3.4e38f, mx = -3.4e38f;
    for (int e = tid; e < SS * SS; e += 256) {
        float v = simb[e]; mn = fminf(mn, v); mx = fmaxf(mx, v);
    }
    __shared__ float rmn[256], rmx[256];
    rmn[tid] = mn; rmx[tid] = mx; __syncthreads();
    for (int o = 128; o > 0; o >>= 1) {
        if (tid < o) { rmn[tid] = fminf(rmn[tid], rmn[tid + o]); rmx[tid] = fmaxf(rmx[tid], rmx[tid + o]); }
        __syncthreads();
    }
    if (tid == 0) { mnmx[0] = rmn[0]; mnmx[1] = rmx[0]; }
}

// ---------- normalize sims in place, deg/dinv ----------
__global__ __launch_bounds__(128) void k_deg(float* __restrict__ simb,
                                             const float* __restrict__ mnmx,
                                             float* __restrict__ deg,
                                             float* __restrict__ dinv) {
    int j = blockIdx.x, i = threadIdx.x;
    float mn = mnmx[0], inv = 1.f / (mnmx[1] - mnmx[0]);
    float s = (simb[i * SS + j] - mn) * inv;
    simb[i * SS + j] = s;
    __shared__ float red[128];
    red[i] = s; __syncthreads();
    for (int o = 64; o > 0; o >>= 1) { if (i < o) red[i] += red[i + o]; __syncthreads(); }
    if (i == 0) { float d = red[0] + 1.f; deg[j] = d; dinv[j] = rsqrtf(d); }
}

// ---------- GCN neighbor aggregate (j<128) ----------
__global__ __launch_bounds__(256) void k_agg(const float* __restrict__ simb,
                                             const float* __restrict__ dinv,
                                             const uint16_t* __restrict__ xw,
                                             float* __restrict__ aggb) {
    int j = blockIdx.x, tid = threadIdx.x;
    __shared__ float w[SS];
    if (tid < SS) w[tid] = dinv[tid] * simb[tid * SS + j] * dinv[j];
    __syncthreads();
    for (int d = tid; d < DD; d += 256) {
        float s = 0.f;
        #pragma unroll 8
        for (int i = 0; i < SS; i++) s += w[i] * b2f(xw[(size_t)i * DD + d]);
        aggb[(size_t)j * DD + d] = s;
    }
}

// ---------- GCN combine in place (bf16 state) ----------
__global__ __launch_bounds__(256) void k_gcn_combine(uint16_t* __restrict__ xw,
                                                     const float* __restrict__ aggb,
                                                     const float* __restrict__ deg,
                                                     const void* __restrict__ gcnb,
                                                     const int* __restrict__ flag) {
    int d = blockIdx.x * 256 + threadIdx.x;
    int n = blockIdx.y;
    size_t t = (size_t)n * DD + d;
    float v = b2f(xw[t]);
    if (n < SS) v = v / deg[n] + aggb[t];
    v += loadf(gcnb, d, flag[0]);
    xw[t] = f2b(fmaxf(v, 0.f));
}

// ---------- colsum over first 128 rows ----------
__global__ __launch_bounds__(256) void k_colsum(const uint16_t* __restrict__ x,
                                                float* __restrict__ svec) {
    int d = blockIdx.x * 256 + threadIdx.x;
    if (d < DD) {
        float s = 0.f;
        for (int i = 0; i < SS; i++) s += b2f(x[(size_t)i * DD + d]);
        svec[d] = s;
    }
}

// ---------- mvec = svec @ ggc_W[l] ----------
__global__ __launch_bounds__(256) void k_matvec(const float* __restrict__ svec,
                                                const void* __restrict__ Wg, size_t ofs,
                                                float* __restrict__ mvec,
                                                const int* __restrict__ flag) {
    int k = blockIdx.x * 256 + threadIdx.x;
    int isf = flag[0];
    if (k < DD) {
        float s = 0.f;
        for (int d = 0; d < DD; d++) s += svec[d] * loadf(Wg, ofs + (size_t)d * DD + k, isf);
        mvec[k] = s;
    }
}

// ---------- giE = mvec @ wih.T + bih ----------
__global__ __launch_bounds__(256) void k_rowdot(const float* __restrict__ mvec,
                                                const void* __restrict__ wih,
                                                const void* __restrict__ bih,
                                                float* __restrict__ giE,
                                                const int* __restrict__ flag) {
    int rr = blockIdx.x, tid = threadIdx.x;
    int isf = flag[0];
    float s = 0.f;
    for (int k = tid; k < DD; k += 256) s += mvec[k] * loadf(wih, (size_t)rr * DD + k, isf);
    __shared__ float red[256];
    red[tid] = s; __syncthreads();
    for (int o = 128; o > 0; o >>= 1) { if (tid < o) red[tid] += red[tid + o]; __syncthreads(); }
    if (tid == 0) giE[rr] = red[0] + loadf(bih, rr, isf);
}

// ---------- y = h_feature + relu(x_g), bf16 store ----------
__global__ __launch_bounds__(256) void k_build_y(const void* __restrict__ hf,
                                                 const uint16_t* __restrict__ xg,
                                                 uint16_t* __restrict__ y,
                                                 const int* __restrict__ flag) {
    int t = blockIdx.x * 256 + threadIdx.x;
    int isf = flag[0];
    if (t < NBSD) y[t] = f2b(loadf(hf, t, isf) + fmaxf(b2f(xg[t]), 0.f));
}

// ---------- LayerNorm -> FLOAT32 output ----------
__global__ __launch_bounds__(256) void k_ln(const uint16_t* __restrict__ tin,
                                            const void* __restrict__ gw,
                                            const void* __restrict__ bw,
                                            float* __restrict__ out,
                                            const int* __restrict__ flag) {
    int m = blockIdx.x, tid = threadIdx.x;
    int isf = flag[0];
    float v0 = b2f(tin[(size_t)m * DD + tid]);
    float v1 = b2f(tin[(size_t)m * DD + tid + 256]);
    float v2 = b2f(tin[(size_t)m * DD + tid + 512]);
    __shared__ float red[256];
    red[tid] = v0 + v1 + v2; __syncthreads();
    for (int o = 128; o > 0; o >>= 1) { if (tid < o) red[tid] += red[tid + o]; __syncthreads(); }
    float mu = red[0] * (1.f / 768.f);
    __syncthreads();
    float d0 = v0 - mu, d1 = v1 - mu, d2 = v2 - mu;
    red[tid] = d0 * d0 + d1 * d1 + d2 * d2; __syncthreads();
    for (int o = 128; o > 0; o >>= 1) { if (tid < o) red[tid] += red[tid + o]; __syncthreads(); }
    float rstd = rsqrtf(red[0] * (1.f / 768.f) + 1e-5f);
    out[(size_t)m * DD + tid]       = d0 * rstd * loadf(gw, tid, isf)       + loadf(bw, tid, isf);
    out[(size_t)m * DD + tid + 256] = d1 * rstd * loadf(gw, tid + 256, isf) + loadf(bw, tid + 256, isf);
    out[(size_t)m * DD + tid + 512] = d2 * rstd * loadf(gw, tid + 512, isf) + loadf(bw, tid + 512, isf);
}

// ---------- simple tiled GEMM: C[M,768](bf16) = A[M,768](bf16) @ W[768,768](raw) ----
enum { EPI_NONE = 0, EPI_BIAS_RELU = 3, EPI_BIAS = 4 };

template<int EPI>
__global__ __launch_bounds__(256)
void k_sgemm(const uint16_t* __restrict__ A, const void* __restrict__ W,
             const void* __restrict__ bias, uint16_t* __restrict__ C,
             const int* __restrict__ flag) {
    __shared__ float As[64][17];
    __shared__ float Ws[16][65];
    int isf = flag[0];
    int tx = threadIdx.x & 15, ty = threadIdx.x >> 4;
    int m0 = blockIdx.y * 64, n0 = blockIdx.x * 64;
    float acc[4][4];
    #pragma unroll
    for (int i = 0; i < 4; i++) for (int j = 0; j < 4; j++) acc[i][j] = 0.f;

    for (int k0 = 0; k0 < DD; k0 += 16) {
        for (int t = threadIdx.x; t < 64 * 16; t += 256) {
            int r = t >> 4, c = t & 15;
            As[r][c] = b2f(A[(size_t)(m0 + r) * DD + k0 + c]);
        }
        for (int t = threadIdx.x; t < 16 * 64; t += 256) {
            int r = t >> 6, c = t & 63;
            Ws[r][c] = loadf(W, (size_t)(k0 + r) * DD + n0 + c, isf);
        }
        __syncthreads();
        #pragma unroll
        for (int kk = 0; kk < 16; kk++)
            #pragma unroll
            for (int i = 0; i < 4; i++)
                #pragma unroll
                for (int j = 0; j < 4; j++)
                    acc[i][j] = fmaf(As[ty * 4 + i][kk], Ws[kk][tx * 4 + j], acc[i][j]);
        __syncthreads();
    }
    #pragma unroll
    for (int i = 0; i < 4; i++)
        #pragma unroll
        for (int j = 0; j < 4; j++) {
            int m = m0 + ty * 4 + i, n = n0 + tx * 4 + j;
            float v = acc[i][j];
            if (EPI == EPI_BIAS_RELU) v = fmaxf(v + loadf(bias, n, isf), 0.f);
            else if (EPI == EPI_BIAS)  v = v + loadf(bias, n, isf);
            C[(size_t)m * DD + n] = f2b(v);
        }
}

// ---------- fused GRU layer (64x64 tile, 3 gates) ----------
__global__ __launch_bounds__(256)
void k_gru2(const uint16_t* __restrict__ X, const void* __restrict__ whh,
            const void* __restrict__ bih, const void* __restrict__ bhh,
            const float* __restrict__ giE, uint16_t* __restrict__ Xn,
            const int* __restrict__ flag) {
    __shared__ float As[64][17];
    __shared__ float Ws[3][16][65];
    int isf = flag[0];
    int tx = threadIdx.x & 15, ty = threadIdx.x >> 4;
    int m0 = blockIdx.y * 64, n0 = blockIdx.x * 64;
    float a0[4][4], a1[4][4], a2[4][4];
    #pragma unroll
    for (int i = 0; i < 4; i++) for (int j = 0; j < 4; j++) { a0[i][j]=0.f; a1[i][j]=0.f; a2[i][j]=0.f; }

    for (int k0 = 0; k0 < DD; k0 += 16) {
        for (int t = threadIdx.x; t < 64 * 16; t += 256) {
            int r = t >> 4, c = t & 15;
            As[r][c] = b2f(X[(size_t)(m0 + r) * DD + k0 + c]);
        }
        for (int t = threadIdx.x; t < 16 * 64; t += 256) {
            int r = t >> 6, c = t & 63;   // r=k offset, c=n offset
            #pragma unroll
            for (int g = 0; g < 3; g++)
                Ws[g][r][c] = loadf(whh, (size_t)(g * DD + n0 + c) * DD + k0 + r, isf);
        }
        __syncthreads();
        #pragma unroll
        for (int kk = 0; kk < 16; kk++) {
            float av[4], b0[4], b1[4], b2v[4];
            #pragma unroll
            for (int i = 0; i < 4; i++) av[i] = As[ty * 4 + i][kk];
            #pragma unroll
            for (int j = 0; j < 4; j++) {
                b0[j] = Ws[0][kk][tx * 4 + j];
                b1[j] = Ws[1][kk][tx * 4 + j];
                b2v[j] = Ws[2][kk][tx * 4 + j];
            }
            #pragma unroll
            for (int i = 0; i < 4; i++)
                #pragma unroll
                for (int j = 0; j < 4; j++) {
                    a0[i][j] = fmaf(av[i], b0[j], a0[i][j]);
                    a1[i][j] = fmaf(av[i], b1[j], a1[i][j]);
                    a2[i][j] = fmaf(av[i], b2v[j], a2[i][j]);
                }
        }
        __syncthreads();
    }
    #pragma unroll
    for (int i = 0; i < 4; i++)
        #pragma unroll
        for (int j = 0; j < 4; j++) {
            int m = m0 + ty * 4 + i, n = n0 + tx * 4 + j;
            bool msg = (m < SS);
            float gr = msg ? giE[n]          : loadf(bih, n, isf);
            float gz = msg ? giE[DD + n]     : loadf(bih, DD + n, isf);
            float gn = msg ? giE[2 * DD + n] : loadf(bih, 2 * DD + n, isf);
            float rg = 1.f / (1.f + expf(-(a0[i][j] + loadf(bhh, n, isf) + gr)));
            float zg = 1.f / (1.f + expf(-(a1[i][j] + loadf(bhh, DD + n, isf) + gz)));
            float hn = a2[i][j] + loadf(bhh, 2 * DD + n, isf);
            float nn = tanhf(gn + rg * hn);
            float xo = b2f(X[(size_t)m * DD + n]);
            Xn[(size_t)m * DD + n] = f2b((1.f - zg) * nn + zg * xo);
        }
}

// ============================== driver ==============================
extern "C" void kernel_launch(void* const* d_in, const int* in_sizes, int n_in,
                              void* d_out, int out_size, void* d_ws, size_t ws_size,
                              hipStream_t stream) {
    float* OUTF = (float*)d_out;            // FINAL output: fp32!
    uint16_t* OB = (uint16_t*)d_out;        // first 18.9MB of d_out reused as bf16 trunk scratch

    // ---- host-side validation ----
    static const int expect[29] = {
        3145728,3145728,3145728,3145728, 589824,768, 1179648, 1769472,1769472, 2304,2304,
        589824,768,589824,768,768,768,
        589824,768,589824,768,768,768,
        589824,768,589824,768,768,768 };
    int bad = -1;
    if (n_in != 29) bad = 90;
    else { for (int i = 0; i < 29; i++) if (in_sizes[i] != expect[i]) { bad = i; break; } }
    if (bad < 0 && out_size != (int)TOTAL_ND) bad = 91;
    if (bad < 0 && ws_size < 33ull * 1024 * 1024) bad = 92;
    if (bad >= 0) {
        k_diag<<<1, 64, 0, stream>>>(OUTF, 10000.f + 100.f * (float)bad);
        return;
    }

    // ws layout: fp32 scratch (476KB) | W0 bf16 [12288,768] | WH bf16 [4096,768] | WT bf16 [4096,768]
    float* fbase = (float*)d_ws;
    float* simb = fbase;                 // 16384
    float* nrm  = simb + 16384;          // 128
    float* mnmx = nrm + 128;             // 2
    float* deg  = mnmx + 2;              // 128
    float* dinv = deg + 128;             // 128
    float* aggb = dinv + 128;            // 98304
    float* svec = aggb + 98304;          // 768
    float* mvec = svec + 768;            // 768
    float* giE  = mvec + 768;            // 2304
    int*   flag = (int*)(giE + 2304);    // 1
    uint16_t* W0 = (uint16_t*)(fbase + 119040);   // 9,437,184 bf16
    uint16_t* WH = W0 + TOTAL_ND;                 // 3,145,728 bf16
    uint16_t* WT = WH + NBSD;                     // 3,145,728 bf16

    const void* hf = d_in[0];
    const void* hc = d_in[1];
    const void* hd = d_in[2];
    const void* hs = d_in[3];

    k_probe<<<1, 64, 0, stream>>>(hf, flag);

    // ---- GCN front-end ----
    k_build_feats<<<NBSD / 256, 256, 0, stream>>>(hc, hd, hs, W0, flag);
    k_nrm2<<<1, 128, 0, stream>>>(hc, hd, hs, nrm, flag);
    k_sim2<<<64, 256, 0, stream>>>(hc, hd, hs, nrm, simb, flag);
    k_minmax<<<1, 256, 0, stream>>>(simb, mnmx);
    k_deg<<<SS, SS, 0, stream>>>(simb, mnmx, deg, dinv);
    k_sgemm<EPI_NONE><<<dim3(12, 192), 256, 0, stream>>>(W0, d_in[4], nullptr, OB, flag);
    k_agg<<<SS, 256, 0, stream>>>(simb, dinv, OB, aggb);
    k_gcn_combine<<<dim3(3, NNODE), 256, 0, stream>>>(OB, aggb, deg, d_in[5], flag);

    // ---- GatedGraphConv: layer 1 OB->W0 (feats dead), layer 2 W0->OB ----
    k_colsum<<<3, 256, 0, stream>>>(OB, svec);
    k_matvec<<<3, 256, 0, stream>>>(svec, d_in[6], 0, mvec, flag);
    k_rowdot<<<2304, 256, 0, stream>>>(mvec, d_in[7], d_in[9], giE, flag);
    k_gru2<<<dim3(12, 192), 256, 0, stream>>>(OB, d_in[8], d_in[9], d_in[10], giE, W0, flag);

    k_colsum<<<3, 256, 0, stream>>>(W0, svec);
    k_matvec<<<3, 256, 0, stream>>>(svec, d_in[6], (size_t)DD * DD, mvec, flag);
    k_rowdot<<<2304, 256, 0, stream>>>(mvec, d_in[7], d_in[9], giE, flag);
    k_gru2<<<dim3(12, 192), 256, 0, stream>>>(W0, d_in[8], d_in[9], d_in[10], giE, OB, flag);

    // ---- build ALL THREE y chunks first (reads OB-bf16 before any fp32 LN write) ----
    for (int g = 0; g < 3; ++g)
        k_build_y<<<NBSD / 256, 256, 0, stream>>>(hf, OB + (size_t)g * NBSD,
                                                  W0 + (size_t)g * NBSD, flag);

    // ---- heads: y -> h1 -> t -> LN (fp32 to d_out; OB scratch now dead) ----
    for (int g = 0; g < 3; ++g) {
        const void* W1 = d_in[11 + 6 * g];
        const void* b1 = d_in[12 + 6 * g];
        const void* W2 = d_in[13 + 6 * g];
        const void* b2 = d_in[14 + 6 * g];
        const void* gw = d_in[15 + 6 * g];
        const void* bw = d_in[16 + 6 * g];
        k_sgemm<EPI_BIAS_RELU><<<dim3(12, 64), 256, 0, stream>>>(W0 + (size_t)g * NBSD, W1, b1, WH, flag);
        k_sgemm<EPI_BIAS><<<dim3(12, 64), 256, 0, stream>>>(WH, W2, b2, WT, flag);
        k_ln<<<NBS, 256, 0, stream>>>(WT, gw, bw, OUTF + (size_t)g * NBSD, flag);
    }
}